// Round 14
// baseline (141.129 us; speedup 1.0000x reference)
//
#include <hip/hip_runtime.h>
#include <hip/hip_bf16.h>

// 1-NN VQ via split-bf16 MFMA + exact fp32 refinement.
//   score[q][k] = csq[k] - 2*dot(q,c_k); out = argmin_k (lowest-k tie-break).
// Phase 0 (knn_prep): codebook -> bf16 hi/lo 32x32-fragment cbB + csq.
// Phase A (knn_mfma): persistent codebook, 32x32x16 MFMA (r23).
//   Ladder: r16 1w=51.5 | r17/r21 2w=39-41 | r18 +barriers=53 | r19 3w cap=69
//   (spill) | r20 bundle=58-64 | r22 4w n-split=41.6 (no spill, occ 28%).
//   r22 lesson: TLP 2->4 changed NOTHING -> no longer latency-bound; pipe-
//   throughput-bound with ~2x overlap inefficiency. Invariant content at
//   16x16x32: 4096 ds_read_b128/CU (~20.5us pipe) + 6144 MFMA (~12.4us).
//   r23 shrinks the pipes, same numerics: 32x32x16 shape -> one A-operand
//   carries 32 q, per-q B-reads HALVE (2048 reads/CU ~10.2us); 32x32 is the
//   faster MFMA (8.07cyc/32k FLOP vs 4.85/16k: 12.4->10.2us).
//   Layouts from VERIFIED 32x32 C/D map (col=lane&31, row=(reg&3)+8*(reg>>2)
//   +4*(lane>>5)) + 16x16 A/B analog: A[m=lane&31][k=(lane>>5)*8+j],
//   B[k=(lane>>5)*8+j][n=lane&31]. Epilogue reduces per 32-lane half
//   (shfl_xor d<=16 stays in-half); half owns one q-row per reg.
//   Config: 512 thr / TLP=2 (proven), pairs split 8 n-tiles 4+4 ->
//   acc[4]x16f=64 AGPR + A 64 + temps ~162 << 256 (no prefetch, safety).
//   Off-kernel merge (r22, proven). Zero steady-state barriers.
// Phase M (knn_merge): per q, union of 2 half-top-2s; out + gap<T worklist.
// Phase B (knn_refine): exact fp32 rescan (u64 keys, lowest-k tie-break).
// Tripwires: fail/absmax>0 => 32x32 layout wrong => revert r21.
//   WRITE >> 5 MB => spill => revert r21.

typedef __bf16 bf16x8 __attribute__((ext_vector_type(8)));
typedef float  floatx16 __attribute__((ext_vector_type(16)));

#define MFMA32 __builtin_amdgcn_mfma_f32_32x32x16_bf16

#define CNT_OFF 0
#define CSQ_OFF 1024
#define CBB_OFF 4096
#define WL_CAP  32768
#define WL_OFF  (4096 + 131072)                  // 135168, 128 KB worklist
#define PBF_OFF (WL_OFF + WL_CAP * 4)            // float2[262144] = 2 MB
#define PBI_OFF (PBF_OFF + 2097152)              // int[262144] = 1 MB
#define T_FLAG  0.004f

typedef __attribute__((address_space(1))) const unsigned int gu32;
typedef __attribute__((address_space(3))) unsigned int lu32;

__device__ __forceinline__ unsigned fmap(float f) {
    unsigned u = __float_as_uint(f);
    return (u & 0x80000000u) ? ~u : (u | 0x80000000u);
}

// ---------------- Phase 0: codebook split, 32x32-fragment layout, csq ----------------
// cbB element index = ((ks*8 + t32)*2 + part)*512 + ln*8 + j   (= id*8)
//   ks = k-step 0..7 (K=16 each); t32 = n-tile 0..7 (32 codes); part 0=hi 1=lo;
//   lane ln: n = t32*32 + (ln&31), k = ks*16 + (ln>>5)*8 + j.
__global__ void knn_prep(const float* __restrict__ cb, __bf16* __restrict__ cbB,
                         float* __restrict__ csq, int* __restrict__ cnt) {
    const int tid = threadIdx.x;
    const int id = blockIdx.x * 256 + tid;       // 0..8191
    if (id == 0) *cnt = 0;
    const int ln = id & 63;
    const int part = (id >> 6) & 1;
    const int frag = id >> 7;                    // ks*8 + t32
    const int t32 = frag & 7;
    const int ks = frag >> 3;
    const int n = t32 * 32 + (ln & 31);
    const int k0 = ks * 16 + (ln >> 5) * 8;
    const float* src = cb + (size_t)n * 128 + k0;
    union { __bf16 h[8]; uint4 u; } p;
#pragma unroll
    for (int j = 0; j < 8; ++j) {
        float f = src[j];
        __bf16 hh = (__bf16)f;
        p.h[j] = (part == 0) ? hh : (__bf16)(f - (float)hh);
    }
    *(uint4*)(cbB + (size_t)id * 8) = p.u;

    if (blockIdx.x == 0) {
        const float4* row = (const float4*)(cb + (size_t)tid * 128);
        float a0 = 0.f, a1 = 0.f, a2 = 0.f, a3 = 0.f;
#pragma unroll 8
        for (int j = 0; j < 32; ++j) {
            float4 v = row[j];
            a0 = fmaf(v.x, v.x, a0);
            a1 = fmaf(v.y, v.y, a1);
            a2 = fmaf(v.z, v.z, a2);
            a3 = fmaf(v.w, v.w, a3);
        }
        csq[tid] = (a0 + a1) + (a2 + a3);
    }
}

// ---------------- Phase A: persistent-codebook 32x32 MFMA, half-top-2 partials ----------------
__global__ __launch_bounds__(512, 2) void knn_mfma(const float* __restrict__ x,
                                                   const __bf16* __restrict__ cbB,
                                                   const float* __restrict__ csq_g,
                                                   float2* __restrict__ pbf,
                                                   int* __restrict__ pbi) {
    __shared__ __bf16 sB[65536];                 // 128 KB: ENTIRE split codebook

    const int tid = threadIdx.x;
    const int wave = tid >> 6;                   // 0..7 (2 waves/SIMD)
    const int lane = tid & 63;
    const int col = lane & 31;                   // n col within 32-tile / q row for A
    const int hi = lane >> 5;                    // k-subgroup bit
    const int pair = wave >> 1;                  // 0..3
    const int half = wave & 1;                   // n-half: tiles half*4 + tt

    // ---- one-time B fill: wave w copies 16 KB (16 x 1 KB, linear) ----
    {
        const char* gsrc = (const char*)cbB + wave * 16384 + lane * 16;
        char* ldst = (char*)sB + wave * 16384;
#pragma unroll
        for (int i = 0; i < 16; ++i)
            __builtin_amdgcn_global_load_lds((gu32*)(gsrc + i * 1024),
                                             (lu32*)(ldst + i * 1024), 16, 0, 0);
    }

    float cs[4];
#pragma unroll
    for (int tt = 0; tt < 4; ++tt) cs[tt] = csq_g[(half * 4 + tt) * 32 + col];

    // ---- 4 batches of 32 q per pair (both half-waves same A) ----
#pragma unroll 1
    for (int bt = 0; bt < 4; ++bt) {
        const size_t q0 = (size_t)blockIdx.x * 512 + bt * 128 + pair * 32;

        // ---- A: load + split-convert; lane holds A[q=col][k=ks*16+hi*8+j] ----
        const float* xq = x + (q0 + col) * 128 + hi * 8;
        bf16x8 ah[8], al[8];
#pragma unroll
        for (int ks = 0; ks < 8; ++ks) {
            float4 f0 = *(const float4*)(xq + ks * 16);
            float4 f1 = *(const float4*)(xq + ks * 16 + 4);
            float f[8] = {f0.x, f0.y, f0.z, f0.w, f1.x, f1.y, f1.z, f1.w};
            union { __bf16 h[8]; bf16x8 v; } phv, plv;
#pragma unroll
            for (int j = 0; j < 8; ++j) {
                __bf16 hh = (__bf16)f[j];
                phv.h[j] = hh;
                plv.h[j] = (__bf16)(f[j] - (float)hh);
            }
            ah[ks] = phv.v;
            al[ks] = plv.v;
        }

        floatx16 acc[4];
#pragma unroll
        for (int tt = 0; tt < 4; ++tt)
#pragma unroll
            for (int e = 0; e < 16; ++e) acc[tt][e] = 0.f;

        if (bt == 0) __syncthreads();            // B fill landed (vmcnt drain), once

        // ---- K-loop: this half's 4 n-tiles, pure LDS reads + MFMA ----
        // fragment (ks, t32=half*4+tt, part) at element ((ks*8+t32)*2+part)*512 + lane*8
#pragma unroll
        for (int ks = 0; ks < 8; ++ks) {
            const __bf16* sbase = sB + (ks * 8 + half * 4) * 1024 + lane * 8;
#pragma unroll
            for (int tt = 0; tt < 4; ++tt) {
                bf16x8 bh = *(const bf16x8*)(sbase + tt * 1024);
                bf16x8 bl = *(const bf16x8*)(sbase + tt * 1024 + 512);
                acc[tt] = MFMA32(ah[ks], bh, acc[tt], 0, 0, 0);
                acc[tt] = MFMA32(al[ks], bh, acc[tt], 0, 0, 0);
                acc[tt] = MFMA32(ah[ks], bl, acc[tt], 0, 0, 0);
            }
        }

        // ---- epilogue: per-half-wave top-2 over this half's 128 codes ----
        // D[q][n]: n = t*32+col, q-row for reg r = (r&3)+8*(r>>2)+4*hi
#pragma unroll
        for (int r = 0; r < 16; ++r) {
            float bf = __builtin_inff(), sf = __builtin_inff();
            int bi = 0;
#pragma unroll
            for (int tt = 0; tt < 4; ++tt) {
                const float sc = fmaf(-2.0f, acc[tt][r], cs[tt]);
                const bool lt = sc < bf;
                sf = lt ? bf : fminf(sf, sc);
                bf = lt ? sc : bf;
                bi = lt ? ((half * 4 + tt) * 32 + col) : bi;
            }
#pragma unroll
            for (int d = 1; d < 32; d <<= 1) {   // reduce within 32-lane half
                const float obf = __shfl_xor(bf, d);
                const int   obi = __shfl_xor(bi, d);
                const float osf = __shfl_xor(sf, d);
                const bool lt = obf < bf;
                const float loser = lt ? bf : obf;           // larger best
                sf = fminf(fminf(sf, osf), loser);
                bf = lt ? obf : bf;
                bi = lt ? obi : bi;
            }
            if (col == 0) {                      // lanes 0 and 32
                const int qrow = (r & 3) + 8 * (r >> 2) + 4 * hi;
                const size_t qg = q0 + qrow;
                pbf[qg * 2 + half] = (float2){bf, sf};
                pbi[qg * 2 + half] = bi;
            }
        }
    }
}

// ---------------- Phase M: merge the two half-top-2s per query ----------------
__global__ __launch_bounds__(256) void knn_merge(const float2* __restrict__ pbf,
                                                 const int* __restrict__ pbi,
                                                 int* __restrict__ out,
                                                 int* __restrict__ cnt,
                                                 int* __restrict__ wl) {
    const int q = blockIdx.x * 256 + threadIdx.x;
    const float4 v = *(const float4*)(pbf + (size_t)q * 2);   // {b0,s0,b1,s1}
    const int2  iv = *(const int2*)(pbi + (size_t)q * 2);
    const bool w0 = v.x < v.z;
    const float B = w0 ? v.x : v.z;
    const float S = fminf(w0 ? v.y : v.w, w0 ? v.z : v.x);
    out[q] = w0 ? iv.x : iv.y;
    if (S - B < T_FLAG) {                        // small gap or tie -> exact pass
        int idx = atomicAdd(cnt, 1);
        if (idx < WL_CAP) wl[idx] = q;
    }
}

// ---------------- Phase B: exact fp32 rescan, block-per-query ----------------
__global__ __launch_bounds__(256) void knn_refine(const float* __restrict__ x,
                                                  const float* __restrict__ cb,
                                                  const float* __restrict__ csq_g,
                                                  const int* __restrict__ wl,
                                                  const int* __restrict__ cnt,
                                                  int* __restrict__ out) {
    __shared__ unsigned long long sP[4];
    const int tid = threadIdx.x;           // == code index k
    const int lane = tid & 63;
    const int wave = tid >> 6;

    int n = *cnt;
    if (n > WL_CAP) n = WL_CAP;
    const float mycsq = csq_g[tid];
    const float4* cr = (const float4*)(cb + (size_t)tid * 128);

    for (int i = blockIdx.x; i < n; i += gridDim.x) {
        const int q = wl[i];
        const float4* qr = (const float4*)(x + (size_t)q * 128);
        float a0 = 0.f, a1 = 0.f, a2 = 0.f, a3 = 0.f;
#pragma unroll 8
        for (int c4 = 0; c4 < 32; ++c4) {
            float4 qv = qr[c4];            // broadcast (same addr all lanes)
            float4 cv = cr[c4];
            a0 = fmaf(qv.x, cv.x, a0);
            a1 = fmaf(qv.y, cv.y, a1);
            a2 = fmaf(qv.z, cv.z, a2);
            a3 = fmaf(qv.w, cv.w, a3);
        }
        float dot = (a0 + a1) + (a2 + a3);
        float score = fmaf(-2.0f, dot, mycsq);
        unsigned long long key =
            ((unsigned long long)fmap(score) << 32) | (unsigned)tid;
#pragma unroll
        for (int d = 1; d < 64; d <<= 1) {
            unsigned long long o = __shfl_xor(key, d);
            key = o < key ? o : key;
        }
        if (lane == 0) sP[wave] = key;
        __syncthreads();
        if (tid == 0) {
            unsigned long long b = sP[0];
            unsigned long long o;
            o = sP[1]; b = o < b ? o : b;
            o = sP[2]; b = o < b ? o : b;
            o = sP[3]; b = o < b ? o : b;
            out[q] = (int)(unsigned)(b & 0xFFFFFFFFull);
        }
        __syncthreads();
    }
}

extern "C" void kernel_launch(void* const* d_in, const int* in_sizes, int n_in,
                              void* d_out, int out_size, void* d_ws, size_t ws_size,
                              hipStream_t stream) {
    const float* x = (const float*)d_in[0];
    const float* cb = (const float*)d_in[1];
    int* out = (int*)d_out;

    char* ws = (char*)d_ws;
    int* cnt = (int*)(ws + CNT_OFF);
    float* csq = (float*)(ws + CSQ_OFF);
    __bf16* cbB = (__bf16*)(ws + CBB_OFF);
    int* wl = (int*)(ws + WL_OFF);
    float2* pbf = (float2*)(ws + PBF_OFF);
    int* pbi = (int*)(ws + PBI_OFF);

    const int M = in_sizes[0] / 128;     // 131072

    knn_prep<<<32, 256, 0, stream>>>(cb, cbB, csq, cnt);
    knn_mfma<<<M / 512, 512, 0, stream>>>(x, cbB, csq, pbf, pbi);
    knn_merge<<<M / 256, 256, 0, stream>>>(pbf, pbi, out, cnt, wl);
    knn_refine<<<240, 256, 0, stream>>>(x, cb, csq, wl, cnt, out);
}

// Round 17
// 132.703 us; speedup vs baseline: 1.0635x; 1.0635x over previous
//
#include <hip/hip_runtime.h>
#include <hip/hip_bf16.h>

// 1-NN VQ via split-bf16 MFMA + exact fp32 refinement.
//   score[q][k] = csq[k] - 2*dot(q,c_k); out = argmin_k (lowest-k tie-break).
// Phase 0 (knn_prep): codebook -> bf16 hi/lo fragment-ready cbB (kb-major) + csq.
// Phase A (knn_mfma): persistent codebook, m=2 wave-pair n-split, no barriers (r24).
//   Ladder: r16 1w=51.5 | r17/r21 2w m=1=39-41 (BEST total 120.2) | r18 2w
//   m=2 +barriers=53 | r19 3w cap spill=69 | r20 bundle=58-64 | r22 4w m=1
//   n-split=41.6 | r23 32x32 shape=53-55 (4 acc chains starve matrix pipe,
//   2x epilogue -- LDS-count halving did NOT help).
//   Synthesis: the 41us floor configs all share per-q 8 B-reads + 16 acc
//   chains. m=2@16x16 halves per-q B-reads keeping 16 chains + cheap
//   epilogue; tried twice, always confounded (r18 barriers, r15 spill).
//   r24 = clean test: r18 minus barriers (r22's off-kernel merge), TLP=2,
//   acc[2][8]=64 AGPR + ah/al 64 ~= 170 regs <= 256 (no spill), ZERO
//   steady-state barriers. Per-CU: ds_read 4096->2048 (~10us), MFMA 6144
//   (12.4us) unchanged.
//   Structure: whole split codebook (128 KB, r21/r22 16x16 kb-major layout)
//   in LDS once (16x gload_lds w=16/wave); ONE barrier (bt==0); 4 batches x
//   (4 pairs x 32 q); wave = half the n-tiles (t = half*8 + tt);
//   dot ~= qh.ch+ql.ch+qh.cl (err ~1.9e-3); float top-2 per half ->
//   partials; ties -> refine exact lowest-k.
// Phase M (knn_merge): per q, union of 2 half-top-2s; out + gap<T worklist.
// Phase B (knn_refine): exact fp32 rescan (u64 keys, lowest-k tie-break).
// Tripwires: WRITE >> 5 MB (3 expected) => spill => revert r21.
//   ~41us again => floor is shared VALU serial content => r21 final.
// (r26 == r24 resubmit #2: broker timeouts r15/r16 -- never executed.)

typedef __bf16 bf16x8 __attribute__((ext_vector_type(8)));
typedef float  floatx4 __attribute__((ext_vector_type(4)));

#define MFMA16 __builtin_amdgcn_mfma_f32_16x16x32_bf16

#define CNT_OFF 0
#define CSQ_OFF 1024
#define CBB_OFF 4096
#define WL_CAP  32768
#define WL_OFF  (4096 + 131072)                  // 135168, 128 KB worklist
#define PBF_OFF (WL_OFF + WL_CAP * 4)            // float2[262144] = 2 MB
#define PBI_OFF (PBF_OFF + 2097152)              // int[262144] = 1 MB
#define T_FLAG  0.004f

typedef __attribute__((address_space(1))) const unsigned int gu32;
typedef __attribute__((address_space(3))) unsigned int lu32;

__device__ __forceinline__ unsigned fmap(float f) {
    unsigned u = __float_as_uint(f);
    return (u & 0x80000000u) ? ~u : (u | 0x80000000u);
}

// ---------------- Phase 0: codebook split, kb-major fragment layout, csq ----------------
// cbB element index = ((kb*16 + t)*2 + part)*512 + ln*8 + j   (= id*8 below)
//   kb = k-chunk 0..3; t = ntile 0..15; part: 0=hi 1=lo;
//   lane ln: n = t*16 + (ln&15), k = kb*32 + (ln>>4)*8 + j.
__global__ void knn_prep(const float* __restrict__ cb, __bf16* __restrict__ cbB,
                         float* __restrict__ csq, int* __restrict__ cnt) {
    const int tid = threadIdx.x;
    const int id = blockIdx.x * 256 + tid;       // 0..8191
    if (id == 0) *cnt = 0;
    const int ln = id & 63;
    const int part = (id >> 6) & 1;
    const int step = id >> 7;                    // kb*16 + t
    const int t4 = step & 15;
    const int kb = step >> 4;
    const int n = t4 * 16 + (ln & 15);
    const int k0 = kb * 32 + (ln >> 4) * 8;
    const float* src = cb + (size_t)n * 128 + k0;
    union { __bf16 h[8]; uint4 u; } p;
#pragma unroll
    for (int j = 0; j < 8; ++j) {
        float f = src[j];
        __bf16 hh = (__bf16)f;
        p.h[j] = (part == 0) ? hh : (__bf16)(f - (float)hh);
    }
    *(uint4*)(cbB + (size_t)id * 8) = p.u;

    if (blockIdx.x == 0) {
        const float4* row = (const float4*)(cb + (size_t)tid * 128);
        float a0 = 0.f, a1 = 0.f, a2 = 0.f, a3 = 0.f;
#pragma unroll 8
        for (int j = 0; j < 32; ++j) {
            float4 v = row[j];
            a0 = fmaf(v.x, v.x, a0);
            a1 = fmaf(v.y, v.y, a1);
            a2 = fmaf(v.z, v.z, a2);
            a3 = fmaf(v.w, v.w, a3);
        }
        csq[tid] = (a0 + a1) + (a2 + a3);
    }
}

// ---------------- Phase A: persistent-codebook MFMA, m=2 half-top-2 partials ----------------
__global__ __launch_bounds__(512, 2) void knn_mfma(const float* __restrict__ x,
                                                   const __bf16* __restrict__ cbB,
                                                   const float* __restrict__ csq_g,
                                                   float2* __restrict__ pbf,
                                                   int* __restrict__ pbi) {
    __shared__ __bf16 sB[32768 * 2];             // 128 KB: ENTIRE split codebook

    const int tid = threadIdx.x;
    const int wave = tid >> 6;                   // 0..7 (2 waves/SIMD)
    const int lane = tid & 63;
    const int rl = lane & 15;                    // n col / q row within tile
    const int kg = lane >> 4;                    // k-group / q-row group 0..3
    const int pair = wave >> 1;                  // 0..3
    const int half = wave & 1;                   // n-half: t = half*8 + tt

    // ---- one-time B fill: wave w copies 16 KB (16 x 1 KB, linear) ----
    {
        const char* gsrc = (const char*)cbB + wave * 16384 + lane * 16;
        char* ldst = (char*)sB + wave * 16384;
#pragma unroll
        for (int i = 0; i < 16; ++i)
            __builtin_amdgcn_global_load_lds((gu32*)(gsrc + i * 1024),
                                             (lu32*)(ldst + i * 1024), 16, 0, 0);
    }

    float cs[8];
#pragma unroll
    for (int tt = 0; tt < 8; ++tt) cs[tt] = csq_g[(half * 8 + tt) * 16 + rl];

    // ---- 4 batches of 32 q per pair (both half-waves same A) ----
#pragma unroll 1
    for (int bt = 0; bt < 4; ++bt) {
        const size_t q0 = (size_t)blockIdx.x * 512 + bt * 128 + pair * 32;

        // ---- A: load + split-convert this pair's 2 m-tiles into registers ----
        const float* xq = x + q0 * 128;
        bf16x8 ah[2][4], al[2][4];
#pragma unroll
        for (int m = 0; m < 2; ++m) {
#pragma unroll
            for (int kb = 0; kb < 4; ++kb) {
                const float* s = xq + (size_t)(m * 16 + rl) * 128 + kb * 32 + kg * 8;
                float4 f0 = *(const float4*)(s);
                float4 f1 = *(const float4*)(s + 4);
                float f[8] = {f0.x, f0.y, f0.z, f0.w, f1.x, f1.y, f1.z, f1.w};
                union { __bf16 h[8]; bf16x8 v; } phv, plv;
#pragma unroll
                for (int j = 0; j < 8; ++j) {
                    __bf16 hh = (__bf16)f[j];
                    phv.h[j] = hh;
                    plv.h[j] = (__bf16)(f[j] - (float)hh);
                }
                ah[m][kb] = phv.v;
                al[m][kb] = plv.v;
            }
        }

        floatx4 acc[2][8];
#pragma unroll
        for (int m = 0; m < 2; ++m)
#pragma unroll
            for (int tt = 0; tt < 8; ++tt) acc[m][tt] = (floatx4){0.f, 0.f, 0.f, 0.f};

        if (bt == 0) __syncthreads();            // B fill landed (vmcnt drain), once

        // ---- K-loop: this half's 8 n-tiles, pure LDS reads + MFMA ----
        // element offset = kb*16384 + (half*8+tt)*1024 + part*512 + lane*8
#pragma unroll
        for (int kb = 0; kb < 4; ++kb) {
            const __bf16* sbase = sB + kb * 16384 + half * 8192 + lane * 8;
#pragma unroll
            for (int tt = 0; tt < 8; ++tt) {
                bf16x8 bh = *(const bf16x8*)(sbase + tt * 1024);
                bf16x8 bl = *(const bf16x8*)(sbase + tt * 1024 + 512);
                acc[0][tt] = MFMA16(ah[0][kb], bh, acc[0][tt], 0, 0, 0);
                acc[1][tt] = MFMA16(ah[1][kb], bh, acc[1][tt], 0, 0, 0);
                acc[0][tt] = MFMA16(al[0][kb], bh, acc[0][tt], 0, 0, 0);
                acc[1][tt] = MFMA16(al[1][kb], bh, acc[1][tt], 0, 0, 0);
                acc[0][tt] = MFMA16(ah[0][kb], bl, acc[0][tt], 0, 0, 0);
                acc[1][tt] = MFMA16(ah[1][kb], bl, acc[1][tt], 0, 0, 0);
            }
        }

        // ---- epilogue: float-domain top-2 over this half's 128 codes ----
#pragma unroll
        for (int m = 0; m < 2; ++m) {
#pragma unroll
            for (int r = 0; r < 4; ++r) {
                float bf = __builtin_inff(), sf = __builtin_inff();
                int bi = 0;
#pragma unroll
                for (int tt = 0; tt < 8; ++tt) {
                    const float sc = fmaf(-2.0f, acc[m][tt][r], cs[tt]);
                    const bool lt = sc < bf;
                    sf = lt ? bf : fminf(sf, sc);
                    bf = lt ? sc : bf;
                    bi = lt ? ((half * 8 + tt) * 16 + rl) : bi;
                }
#pragma unroll
                for (int d = 1; d < 16; d <<= 1) {
                    const float obf = __shfl_xor(bf, d);
                    const int   obi = __shfl_xor(bi, d);
                    const float osf = __shfl_xor(sf, d);
                    const bool lt = obf < bf;
                    const float loser = lt ? bf : obf;       // larger best
                    sf = fminf(fminf(sf, osf), loser);
                    bf = lt ? obf : bf;
                    bi = lt ? obi : bi;
                }
                if (rl == 0) {
                    const size_t qg = q0 + m * 16 + kg * 4 + r;
                    pbf[qg * 2 + half] = (float2){bf, sf};
                    pbi[qg * 2 + half] = bi;
                }
            }
        }
    }
}

// ---------------- Phase M: merge the two half-top-2s per query ----------------
__global__ __launch_bounds__(256) void knn_merge(const float2* __restrict__ pbf,
                                                 const int* __restrict__ pbi,
                                                 int* __restrict__ out,
                                                 int* __restrict__ cnt,
                                                 int* __restrict__ wl) {
    const int q = blockIdx.x * 256 + threadIdx.x;
    const float4 v = *(const float4*)(pbf + (size_t)q * 2);   // {b0,s0,b1,s1}
    const int2  iv = *(const int2*)(pbi + (size_t)q * 2);
    const bool w0 = v.x < v.z;
    const float B = w0 ? v.x : v.z;
    const float S = fminf(w0 ? v.y : v.w, w0 ? v.z : v.x);
    out[q] = w0 ? iv.x : iv.y;
    if (S - B < T_FLAG) {                        // small gap or tie -> exact pass
        int idx = atomicAdd(cnt, 1);
        if (idx < WL_CAP) wl[idx] = q;
    }
}

// ---------------- Phase B: exact fp32 rescan, block-per-query ----------------
__global__ __launch_bounds__(256) void knn_refine(const float* __restrict__ x,
                                                  const float* __restrict__ cb,
                                                  const float* __restrict__ csq_g,
                                                  const int* __restrict__ wl,
                                                  const int* __restrict__ cnt,
                                                  int* __restrict__ out) {
    __shared__ unsigned long long sP[4];
    const int tid = threadIdx.x;           // == code index k
    const int lane = tid & 63;
    const int wave = tid >> 6;

    int n = *cnt;
    if (n > WL_CAP) n = WL_CAP;
    const float mycsq = csq_g[tid];
    const float4* cr = (const float4*)(cb + (size_t)tid * 128);

    for (int i = blockIdx.x; i < n; i += gridDim.x) {
        const int q = wl[i];
        const float4* qr = (const float4*)(x + (size_t)q * 128);
        float a0 = 0.f, a1 = 0.f, a2 = 0.f, a3 = 0.f;
#pragma unroll 8
        for (int c4 = 0; c4 < 32; ++c4) {
            float4 qv = qr[c4];            // broadcast (same addr all lanes)
            float4 cv = cr[c4];
            a0 = fmaf(qv.x, cv.x, a0);
            a1 = fmaf(qv.y, cv.y, a1);
            a2 = fmaf(qv.z, cv.z, a2);
            a3 = fmaf(qv.w, cv.w, a3);
        }
        float dot = (a0 + a1) + (a2 + a3);
        float score = fmaf(-2.0f, dot, mycsq);
        unsigned long long key =
            ((unsigned long long)fmap(score) << 32) | (unsigned)tid;
#pragma unroll
        for (int d = 1; d < 64; d <<= 1) {
            unsigned long long o = __shfl_xor(key, d);
            key = o < key ? o : key;
        }
        if (lane == 0) sP[wave] = key;
        __syncthreads();
        if (tid == 0) {
            unsigned long long b = sP[0];
            unsigned long long o;
            o = sP[1]; b = o < b ? o : b;
            o = sP[2]; b = o < b ? o : b;
            o = sP[3]; b = o < b ? o : b;
            out[q] = (int)(unsigned)(b & 0xFFFFFFFFull);
        }
        __syncthreads();
    }
}

extern "C" void kernel_launch(void* const* d_in, const int* in_sizes, int n_in,
                              void* d_out, int out_size, void* d_ws, size_t ws_size,
                              hipStream_t stream) {
    const float* x = (const float*)d_in[0];
    const float* cb = (const float*)d_in[1];
    int* out = (int*)d_out;

    char* ws = (char*)d_ws;
    int* cnt = (int*)(ws + CNT_OFF);
    float* csq = (float*)(ws + CSQ_OFF);
    __bf16* cbB = (__bf16*)(ws + CBB_OFF);
    int* wl = (int*)(ws + WL_OFF);
    float2* pbf = (float2*)(ws + PBF_OFF);
    int* pbi = (int*)(ws + PBI_OFF);

    const int M = in_sizes[0] / 128;     // 131072

    knn_prep<<<32, 256, 0, stream>>>(cb, cbB, csq, cnt);
    knn_mfma<<<M / 512, 512, 0, stream>>>(x, cbB, csq, pbf, pbi);
    knn_merge<<<M / 256, 256, 0, stream>>>(pbf, pbi, out, cnt, wl);
    knn_refine<<<240, 256, 0, stream>>>(x, cb, csq, wl, cnt, out);
}

// Round 18
// 119.692 us; speedup vs baseline: 1.1791x; 1.1087x over previous
//
#include <hip/hip_runtime.h>
#include <hip/hip_bf16.h>

// 1-NN VQ via split-bf16 MFMA + exact fp32 refinement.  [r27 == r21, FINAL]
//   score[q][k] = csq[k] - 2*dot(q,c_k); out = argmin_k (lowest-k tie-break).
// Phase 0 (knn_prep): codebook -> bf16 hi/lo fragment-ready cbB (kb-major) + csq.
// Phase A (knn_mfma): persistent codebook, 2 w/SIMD lockstep + A-prefetch.
//   FINAL LADDER (knn_mfma warm us): r16 1w=51.5 | r17 2w=39-41 | r18 m=2+
//   barriers=53 | r19 3w reg-cap=69 (acc->scratch) | r20 bundle=58-64 |
//   *r21 2w+prefetch=41.2 BEST (total 120.2)* | r22 4w n-split=41.6 |
//   r23 32x32=53-55 | r24 m=2 clean=46 (null: B-read halving never helps).
//   Conclusion: floor ~41us is shared per-q serial content (A-convert +
//   epilogue chains) at 2w/SIMD; every lever (TLP 1/2/3/4, B-read halving
//   x3 ways, MFMA shape, antiphase, setprio, barriers) HW-falsified.
//   Remaining total is harness fillBuffer resets (4x41us, uncontrollable).
//   Structure: whole split codebook (128 KB) in LDS once (16x gload_lds
//   w=16/wave, linear dest); ONE barrier ever (bt==0); 4 batches x 16 q per
//   wave (m=1, all 16 n-tiles); K-loop pure ds_read_b128+MFMA; T14
//   issue-early/convert-late A-prefetch hides x-load latency under epilogue;
//   dot ~= qh.ch+ql.ch+qh.cl (err ~1.9e-3); float-domain top-2, gap <
//   T=0.004 -> worklist (ties -> refine exact lowest-k pass).
// Phase B (knn_refine): exact fp32 rescan (u64 keys, lowest-k tie-break).

typedef __bf16 bf16x8 __attribute__((ext_vector_type(8)));
typedef float  floatx4 __attribute__((ext_vector_type(4)));

#define MFMA16 __builtin_amdgcn_mfma_f32_16x16x32_bf16

#define CNT_OFF 0
#define CSQ_OFF 1024
#define CBB_OFF 4096
#define WL_OFF  (4096 + 131072)
#define WL_CAP  32768
#define T_FLAG  0.004f

typedef __attribute__((address_space(1))) const unsigned int gu32;
typedef __attribute__((address_space(3))) unsigned int lu32;

__device__ __forceinline__ unsigned fmap(float f) {
    unsigned u = __float_as_uint(f);
    return (u & 0x80000000u) ? ~u : (u | 0x80000000u);
}

// ---------------- Phase 0: codebook split, kb-major fragment layout, csq ----------------
// cbB element index = ((kb*16 + t)*2 + part)*512 + ln*8 + j   (= id*8 below)
//   kb = k-chunk 0..3; t = ntile 0..15; part: 0=hi 1=lo;
//   lane ln: n = t*16 + (ln&15), k = kb*32 + (ln>>4)*8 + j.
__global__ void knn_prep(const float* __restrict__ cb, __bf16* __restrict__ cbB,
                         float* __restrict__ csq, int* __restrict__ cnt) {
    const int tid = threadIdx.x;
    const int id = blockIdx.x * 256 + tid;       // 0..8191
    if (id == 0) *cnt = 0;
    const int ln = id & 63;
    const int part = (id >> 6) & 1;
    const int step = id >> 7;                    // kb*16 + t
    const int t4 = step & 15;
    const int kb = step >> 4;
    const int n = t4 * 16 + (ln & 15);
    const int k0 = kb * 32 + (ln >> 4) * 8;
    const float* src = cb + (size_t)n * 128 + k0;
    union { __bf16 h[8]; uint4 u; } p;
#pragma unroll
    for (int j = 0; j < 8; ++j) {
        float f = src[j];
        __bf16 hh = (__bf16)f;
        p.h[j] = (part == 0) ? hh : (__bf16)(f - (float)hh);
    }
    *(uint4*)(cbB + (size_t)id * 8) = p.u;

    if (blockIdx.x == 0) {
        const float4* row = (const float4*)(cb + (size_t)tid * 128);
        float a0 = 0.f, a1 = 0.f, a2 = 0.f, a3 = 0.f;
#pragma unroll 8
        for (int j = 0; j < 32; ++j) {
            float4 v = row[j];
            a0 = fmaf(v.x, v.x, a0);
            a1 = fmaf(v.y, v.y, a1);
            a2 = fmaf(v.z, v.z, a2);
            a3 = fmaf(v.w, v.w, a3);
        }
        csq[tid] = (a0 + a1) + (a2 + a3);
    }
}

// ---------------- Phase A: persistent-codebook MFMA scores + top-2 + flag ----------------
__global__ __launch_bounds__(512, 2) void knn_mfma(const float* __restrict__ x,
                                                   const __bf16* __restrict__ cbB,
                                                   const float* __restrict__ csq_g,
                                                   int* __restrict__ out,
                                                   int* __restrict__ cnt,
                                                   int* __restrict__ wl) {
    __shared__ __bf16 sB[65536];                 // 128 KB: ENTIRE split codebook

    const int tid = threadIdx.x;
    const int wave = tid >> 6;                   // 0..7 (2 waves/SIMD, lockstep)
    const int lane = tid & 63;
    const int rl = lane & 15;                    // n col within tile
    const int kg = lane >> 4;                    // k-group / q-row group 0..3

    const size_t qbase = (size_t)blockIdx.x * 512 + wave * 16;
    const float* xw = x + (qbase + rl) * 128 + kg * 8;   // per-lane A row base

    // ---- prefetch A for batch 0 (issued before the B fill) ----
    float4 pf[8];
#pragma unroll
    for (int kb = 0; kb < 4; ++kb) {
        pf[2 * kb]     = *(const float4*)(xw + kb * 32);
        pf[2 * kb + 1] = *(const float4*)(xw + kb * 32 + 4);
    }

    // ---- one-time B fill: wave w copies 16 KB (16 x 1 KB, linear) ----
    {
        const char* gsrc = (const char*)cbB + wave * 16384 + lane * 16;
        char* ldst = (char*)sB + wave * 16384;
#pragma unroll
        for (int i = 0; i < 16; ++i)
            __builtin_amdgcn_global_load_lds((gu32*)(gsrc + i * 1024),
                                             (lu32*)(ldst + i * 1024), 16, 0, 0);
    }

    float cs[16];
#pragma unroll
    for (int t = 0; t < 16; ++t) cs[t] = csq_g[t * 16 + rl];   // L1-hot, once

    // ---- 4 batches of 16 q per wave (lockstep, no reordering) ----
#pragma unroll 1
    for (int bt = 0; bt < 4; ++bt) {
        const size_t q0 = qbase + (size_t)bt * 128;

        // ---- convert prefetched A: split into bf16 hi/lo fragments ----
        bf16x8 ah[4], al[4];
#pragma unroll
        for (int kb = 0; kb < 4; ++kb) {
            const float4 f0 = pf[2 * kb];
            const float4 f1 = pf[2 * kb + 1];
            float f[8] = {f0.x, f0.y, f0.z, f0.w, f1.x, f1.y, f1.z, f1.w};
            union { __bf16 h[8]; bf16x8 v; } phv, plv;
#pragma unroll
            for (int j = 0; j < 8; ++j) {
                __bf16 hh = (__bf16)f[j];
                phv.h[j] = hh;
                plv.h[j] = (__bf16)(f[j] - (float)hh);
            }
            ah[kb] = phv.v;
            al[kb] = plv.v;
        }

        floatx4 acc[16];
#pragma unroll
        for (int t = 0; t < 16; ++t) acc[t] = (floatx4){0.f, 0.f, 0.f, 0.f};

        if (bt == 0) __syncthreads();            // B fill landed (vmcnt drain), once

        // ---- K-loop: pure LDS reads + MFMA, no barriers, no setprio ----
        // element offset = kb*16384 + t*1024 + part*512 + lane*8
#pragma unroll
        for (int kb = 0; kb < 4; ++kb) {
            const __bf16* sbase = sB + kb * 16384 + lane * 8;
#pragma unroll
            for (int t = 0; t < 16; ++t) {
                bf16x8 bh = *(const bf16x8*)(sbase + t * 1024);
                bf16x8 bl = *(const bf16x8*)(sbase + t * 1024 + 512);
                acc[t] = MFMA16(ah[kb], bh, acc[t], 0, 0, 0);
                acc[t] = MFMA16(al[kb], bh, acc[t], 0, 0, 0);
                acc[t] = MFMA16(ah[kb], bl, acc[t], 0, 0, 0);
            }
        }

        // ---- issue next batch's A loads (latency hides under epilogue) ----
        if (bt < 3) {
            const float* xs = xw + (size_t)(bt + 1) * 128 * 128;
#pragma unroll
            for (int kb = 0; kb < 4; ++kb) {
                pf[2 * kb]     = *(const float4*)(xs + kb * 32);
                pf[2 * kb + 1] = *(const float4*)(xs + kb * 32 + 4);
            }
        }

        // ---- epilogue: float-domain per-wave top-2 (ties -> refine) ----
#pragma unroll
        for (int r = 0; r < 4; ++r) {
            float bf = __builtin_inff(), sf = __builtin_inff();
            int bi = 0;
#pragma unroll
            for (int t = 0; t < 16; ++t) {
                const float sc = fmaf(-2.0f, acc[t][r], cs[t]);
                const bool lt = sc < bf;
                sf = lt ? bf : fminf(sf, sc);
                bf = lt ? sc : bf;
                bi = lt ? (t * 16 + rl) : bi;
            }
#pragma unroll
            for (int d = 1; d < 16; d <<= 1) {
                const float obf = __shfl_xor(bf, d);
                const int   obi = __shfl_xor(bi, d);
                const float osf = __shfl_xor(sf, d);
                const bool lt = obf < bf;
                const float loser = lt ? bf : obf;           // larger best
                sf = fminf(fminf(sf, osf), loser);
                bf = lt ? obf : bf;
                bi = lt ? obi : bi;
            }
            if (rl == 0) {
                const size_t qg = q0 + kg * 4 + r;
                out[qg] = bi;
                if (sf - bf < T_FLAG) {          // gap small (or tie) -> exact pass
                    int idx = atomicAdd(cnt, 1);
                    if (idx < WL_CAP) wl[idx] = (int)qg;
                }
            }
        }
    }
}

// ---------------- Phase B: exact fp32 rescan, block-per-query ----------------
__global__ __launch_bounds__(256) void knn_refine(const float* __restrict__ x,
                                                  const float* __restrict__ cb,
                                                  const float* __restrict__ csq_g,
                                                  const int* __restrict__ wl,
                                                  const int* __restrict__ cnt,
                                                  int* __restrict__ out) {
    __shared__ unsigned long long sP[4];
    const int tid = threadIdx.x;           // == code index k
    const int lane = tid & 63;
    const int wave = tid >> 6;

    int n = *cnt;
    if (n > WL_CAP) n = WL_CAP;
    const float mycsq = csq_g[tid];
    const float4* cr = (const float4*)(cb + (size_t)tid * 128);

    for (int i = blockIdx.x; i < n; i += gridDim.x) {
        const int q = wl[i];
        const float4* qr = (const float4*)(x + (size_t)q * 128);
        float a0 = 0.f, a1 = 0.f, a2 = 0.f, a3 = 0.f;
#pragma unroll 8
        for (int c4 = 0; c4 < 32; ++c4) {
            float4 qv = qr[c4];            // broadcast (same addr all lanes)
            float4 cv = cr[c4];
            a0 = fmaf(qv.x, cv.x, a0);
            a1 = fmaf(qv.y, cv.y, a1);
            a2 = fmaf(qv.z, cv.z, a2);
            a3 = fmaf(qv.w, cv.w, a3);
        }
        float dot = (a0 + a1) + (a2 + a3);
        float score = fmaf(-2.0f, dot, mycsq);
        unsigned long long key =
            ((unsigned long long)fmap(score) << 32) | (unsigned)tid;
#pragma unroll
        for (int d = 1; d < 64; d <<= 1) {
            unsigned long long o = __shfl_xor(key, d);
            key = o < key ? o : key;
        }
        if (lane == 0) sP[wave] = key;
        __syncthreads();
        if (tid == 0) {
            unsigned long long b = sP[0];
            unsigned long long o;
            o = sP[1]; b = o < b ? o : b;
            o = sP[2]; b = o < b ? o : b;
            o = sP[3]; b = o < b ? o : b;
            out[q] = (int)(unsigned)(b & 0xFFFFFFFFull);
        }
        __syncthreads();
    }
}

extern "C" void kernel_launch(void* const* d_in, const int* in_sizes, int n_in,
                              void* d_out, int out_size, void* d_ws, size_t ws_size,
                              hipStream_t stream) {
    const float* x = (const float*)d_in[0];
    const float* cb = (const float*)d_in[1];
    int* out = (int*)d_out;

    char* ws = (char*)d_ws;
    int* cnt = (int*)(ws + CNT_OFF);
    float* csq = (float*)(ws + CSQ_OFF);
    __bf16* cbB = (__bf16*)(ws + CBB_OFF);
    int* wl = (int*)(ws + WL_OFF);

    const int M = in_sizes[0] / 128;     // 131072

    knn_prep<<<32, 256, 0, stream>>>(cb, cbB, csq, cnt);
    knn_mfma<<<M / 512, 512, 0, stream>>>(x, cbB, csq, out, cnt, wl);
    knn_refine<<<240, 256, 0, stream>>>(x, cb, csq, wl, cnt, out);
}